// Round 6
// baseline (617.330 us; speedup 1.0000x reference)
//
#include <hip/hip_runtime.h>
#include <hip/hip_bf16.h>
#include <math.h>

#define B_    8
#define L_    2048
#define HID   768
#define D2    384
#define NUV   1792
#define R_    16384
#define SCALE 0.08838834764831845f  // 128^-0.5

typedef __attribute__((ext_vector_type(8))) short bf16x8;
typedef __attribute__((ext_vector_type(4))) float f32x4;
typedef unsigned int uint32;
typedef unsigned short ushort;

static __device__ __forceinline__ uint32 bfr(float x) {
    uint32 u = __float_as_uint(x);
    return (u + 0x7FFFu + ((u >> 16) & 1u)) >> 16;
}
static __device__ __forceinline__ uint32 pk2(float lo, float hi) {
    return bfr(lo) | (bfr(hi) << 16);
}
static __device__ __forceinline__ float bf2f(ushort u) {
    return __uint_as_float(((uint32)u) << 16);
}
static __device__ __forceinline__ float silu_f(float x) { return x / (1.0f + __expf(-x)); }

// ---------------------------------------------------------------------------
// Weight pre-transform: Thi/Tlo[n][k] = bf16 hi/lo split of W[k][n]
// ---------------------------------------------------------------------------
__global__ __launch_bounds__(256) void conv_w(const float* __restrict__ W,
                                              ushort* __restrict__ Thi,
                                              ushort* __restrict__ Tlo,
                                              int K, int N)
{
    int idx = blockIdx.x * 256 + threadIdx.x;
    if (idx >= K * N) return;
    int n = idx / K, k = idx - n * K;
    float x = W[(size_t)k * N + n];
    uint32 h = bfr(x);
    float hf = __uint_as_float(h << 16);
    Thi[idx] = (ushort)h;
    Tlo[idx] = (ushort)bfr(x - hf);
}

// ---------------------------------------------------------------------------
// Split-bf16 MFMA GEMM (3-pass hi/lo). B pre-transposed+split [N][K] bf16.
// Block 512 thr (8 waves), tile 128x128, BK=64.
// EPI 0: C f32     EPI 1: GAU GEMM1 epilogue (u/v/qk by n0)
// ---------------------------------------------------------------------------
template<int EPI>
__global__ __launch_bounds__(512, 4) void gemm_mfma(
    const float* __restrict__ A, int lda,
    const ushort* __restrict__ BThi, const ushort* __restrict__ BTlo, int ldbt,
    float* __restrict__ C, int ldc,
    ushort* __restrict__ qk, ushort* __restrict__ vT, int K)
{
    __shared__ unsigned char As[128 * 256];
    __shared__ unsigned char Bs[128 * 256];

    const int t  = threadIdx.x;
    const int w  = t >> 6;
    const int l  = t & 63;
    const int g  = l >> 4;
    const int li = l & 15;
    const int wr = w >> 1;
    const int wc = w & 1;
    const int m0 = blockIdx.y * 128;
    const int n0 = blockIdx.x * 128;

    f32x4 acc[2][4];
#pragma unroll
    for (int i = 0; i < 2; ++i)
#pragma unroll
        for (int j = 0; j < 4; ++j) acc[i][j] = (f32x4){0.f, 0.f, 0.f, 0.f};

    for (int k0 = 0; k0 < K; k0 += 64) {
#pragma unroll
        for (int i = 0; i < 4; ++i) {
            int idx = t + i * 512;
            int r   = idx >> 4;
            int c16 = idx & 15;
            float4 v = *(const float4*)(A + (long long)(m0 + r) * lda + k0 + c16 * 4);
            uint2 h; h.x = pk2(v.x, v.y); h.y = pk2(v.z, v.w);
            float hx = __uint_as_float((h.x & 0xFFFFu) << 16), hy = __uint_as_float(h.x & 0xFFFF0000u);
            float hz = __uint_as_float((h.y & 0xFFFFu) << 16), hw = __uint_as_float(h.y & 0xFFFF0000u);
            uint2 lo; lo.x = pk2(v.x - hx, v.y - hy); lo.y = pk2(v.z - hz, v.w - hw);
            int sw = (c16 * 8) ^ ((r & 7) << 4);
            *(uint2*)&As[r * 256 + sw]       = h;
            *(uint2*)&As[r * 256 + 128 + sw] = lo;
        }
#pragma unroll
        for (int i = 0; i < 8; ++i) {
            int idx = t + i * 512;
            int c   = idx >> 5;
            int s8  = idx & 31;
            const ushort* src = (s8 < 16)
                ? (BThi + (long long)(n0 + c) * ldbt + k0 + s8 * 4)
                : (BTlo + (long long)(n0 + c) * ldbt + k0 + (s8 - 16) * 4);
            *(uint2*)&Bs[c * 256 + ((s8 * 8) ^ ((c & 7) << 4))] = *(const uint2*)src;
        }
        __syncthreads();

#pragma unroll
        for (int ks = 0; ks < 2; ++ks) {
            bf16x8 ah[2], al[2], bh[4], bl[4];
#pragma unroll
            for (int mi = 0; mi < 2; ++mi) {
                int row = wr * 32 + mi * 16 + li;
                int off = (ks * 64 + g * 16) ^ ((row & 7) << 4);
                ah[mi] = *(const bf16x8*)&As[row * 256 + off];
                al[mi] = *(const bf16x8*)&As[row * 256 + 128 + off];
            }
#pragma unroll
            for (int ni = 0; ni < 4; ++ni) {
                int col = wc * 64 + ni * 16 + li;
                int off = (ks * 64 + g * 16) ^ ((col & 7) << 4);
                bh[ni] = *(const bf16x8*)&Bs[col * 256 + off];
                bl[ni] = *(const bf16x8*)&Bs[col * 256 + 128 + off];
            }
#pragma unroll
            for (int mi = 0; mi < 2; ++mi)
#pragma unroll
                for (int ni = 0; ni < 4; ++ni) {
                    acc[mi][ni] = __builtin_amdgcn_mfma_f32_16x16x32_bf16(ah[mi], bh[ni], acc[mi][ni], 0, 0, 0);
                    acc[mi][ni] = __builtin_amdgcn_mfma_f32_16x16x32_bf16(ah[mi], bl[ni], acc[mi][ni], 0, 0, 0);
                    acc[mi][ni] = __builtin_amdgcn_mfma_f32_16x16x32_bf16(al[mi], bh[ni], acc[mi][ni], 0, 0, 0);
                }
        }
        __syncthreads();
    }

    if (EPI == 0) {
#pragma unroll
        for (int mi = 0; mi < 2; ++mi)
#pragma unroll
            for (int ni = 0; ni < 4; ++ni) {
                int col = n0 + wc * 64 + ni * 16 + li;
#pragma unroll
                for (int r = 0; r < 4; ++r) {
                    int row = m0 + wr * 32 + mi * 16 + g * 4 + r;
                    C[(long long)row * ldc + col] = acc[mi][ni][r];
                }
            }
    } else {
        if (n0 < 768) {
#pragma unroll
            for (int mi = 0; mi < 2; ++mi)
#pragma unroll
                for (int ni = 0; ni < 4; ++ni) {
                    int col = n0 + wc * 64 + ni * 16 + li;
#pragma unroll
                    for (int r = 0; r < 4; ++r) {
                        int row = m0 + wr * 32 + mi * 16 + g * 4 + r;
                        C[(long long)row * 768 + col] = silu_f(acc[mi][ni][r]);
                    }
                }
        } else if (n0 < 1536) {
            int bb = m0 >> 11;
            int llb = (m0 & 2047) + wr * 32 + g * 4;
#pragma unroll
            for (int mi = 0; mi < 2; ++mi) {
                int ll = llb + mi * 16;
#pragma unroll
                for (int ni = 0; ni < 4; ++ni) {
                    int cv = n0 + wc * 64 + ni * 16 + li - 768;
                    ushort* vb = vT + ((size_t)bb * 768 + cv) * 2048 + ll;
                    *(uint32*)(vb)     = pk2(silu_f(acc[mi][ni][0]), silu_f(acc[mi][ni][1]));
                    *(uint32*)(vb + 2) = pk2(silu_f(acc[mi][ni][2]), silu_f(acc[mi][ni][3]));
                }
            }
        } else {
#pragma unroll
            for (int mi = 0; mi < 2; ++mi)
#pragma unroll
                for (int ni = 0; ni < 4; ++ni) {
                    int qcol = n0 + wc * 64 + ni * 16 + li - 1536;
#pragma unroll
                    for (int r = 0; r < 4; ++r) {
                        int row = m0 + wr * 32 + mi * 16 + g * 4 + r;
                        qk[(size_t)row * 256 + qcol] = (ushort)bfr(acc[mi][ni][r]);
                    }
                }
        }
    }
}

// ---------------------------------------------------------------------------
// RoPE in place on bf16 qk buffer (q cols 0..127, k cols 128..255)
// ---------------------------------------------------------------------------
__global__ __launch_bounds__(128) void rope_bf(ushort* __restrict__ qk,
                                               const float* __restrict__ pos)
{
    int row = blockIdx.x;
    int lpos = row & (L_ - 1);
    int t = threadIdx.x;
    int j = t & 63;
    int isK = t >> 6;
    ushort* base = qk + (size_t)row * 256 + isK * 128;
    float s = pos[lpos * 256 + j];
    float c = pos[lpos * 256 + 64 + j];
    float x1 = bf2f(base[j]);
    float x2 = bf2f(base[64 + j]);
    base[j]      = (ushort)bfr(x1 * c - x2 * s);
    base[64 + j] = (ushort)bfr(x2 * c + x1 * s);
}

// ---------------------------------------------------------------------------
// MFMA flash attention v3 — occupancy-doubled.
// QBLK=16 q-rows/block, grid 1024 (4 blocks/CU), 512 thr (8 waves).
// QK: wave w -> S cols (w&3)*16..+16, K-half (w>>2)*64; partials in f32 LDS.
// PV: wave w -> V-cols w*96..+96, o[6] (24 VGPR).
// 3 barriers/tile; gates u_buf in place.
// ---------------------------------------------------------------------------
__global__ __launch_bounds__(512, 8) void fused_attn3(
    float* __restrict__ u_buf, const ushort* __restrict__ qk,
    const ushort* __restrict__ vT)
{
    __shared__ unsigned char KbB[64 * 256];     // K tile bf16 [64][128], swizzled
    __shared__ float Ps[2][16][68];             // S partials (per K-half)
    __shared__ unsigned char PbB[16 * 128];     // P bf16 [16][64], swizzled
    __shared__ float mrun[16], lrun[16], ratio_s[16];

    const int t  = threadIdx.x;
    const int w  = t >> 6;
    const int l  = t & 63;
    const int g  = l >> 4;
    const int li = l & 15;

    const int b  = blockIdx.x & 7;              // XCD-pinned batch
    const int qt = blockIdx.x >> 3;             // 0..127
    const long long rowQ0 = (long long)b * L_ + (long long)qt * 16;
    const long long rowB0 = (long long)b * L_;

    const int cw = w & 3;    // S col-tile (key group)
    const int kh = w >> 2;   // K-half (0: d 0..63, 1: d 64..127)

    // Q A-fragments for this wave's K-half (2x K=32 chunks)
    bf16x8 qf[2];
    {
        const ushort* qrow = qk + (rowQ0 + li) * 256;
#pragma unroll
        for (int ks = 0; ks < 2; ++ks)
            qf[ks] = *(const bf16x8*)&qrow[kh * 64 + ks * 32 + g * 8];
    }
    if (t < 16) { mrun[t] = -3.0e38f; lrun[t] = 0.0f; }

    f32x4 o[6];
#pragma unroll
    for (int ct = 0; ct < 6; ++ct) o[ct] = (f32x4){0.f, 0.f, 0.f, 0.f};

    const ushort* vrow = vT + ((size_t)b * 768 + w * 96 + li) * 2048 + g * 8;

    for (int jt = 0; jt < L_ / 64; ++jt) {
        // ---- stage K tile (64 keys x 128 d, bf16, swizzled) ----
#pragma unroll
        for (int it = 0; it < 2; ++it) {
            int idx = it * 512 + t;
            int r   = idx >> 4;
            int s16 = idx & 15;
            uint4 v = *(const uint4*)&qk[(rowB0 + jt * 64 + r) * 256 + 128 + s16 * 8];
            *(uint4*)&KbB[r * 256 + ((s16 * 16) ^ ((r & 7) << 4))] = v;
        }
        __syncthreads();   // (A) Kb ready

        // ---- QK: 16x16 S-tile, K=64 partial per wave ----
        {
            f32x4 s = {0.f, 0.f, 0.f, 0.f};
            const int krow = cw * 16 + li;
#pragma unroll
            for (int ks = 0; ks < 2; ++ks) {
                bf16x8 kf = *(const bf16x8*)&KbB[krow * 256 +
                                ((kh * 128 + ks * 64 + g * 16) ^ ((krow & 7) << 4))];
                s = __builtin_amdgcn_mfma_f32_16x16x32_bf16(qf[ks], kf, s, 0, 0, 0);
            }
#pragma unroll
            for (int r = 0; r < 4; ++r)
                Ps[kh][g * 4 + r][cw * 16 + li] = s[r];
        }
        __syncthreads();   // (B) Ps ready

        // ---- online softmax: 32 lanes/row, 2 cols each ----
        {
            int row = t >> 5;
            int cl  = t & 31;
            float2 a0 = *(const float2*)&Ps[0][row][cl * 2];
            float2 a1 = *(const float2*)&Ps[1][row][cl * 2];
            float x0 = a0.x + a1.x, x1 = a0.y + a1.y;
            float mx = fmaxf(x0, x1);
#pragma unroll
            for (int off = 16; off >= 1; off >>= 1) mx = fmaxf(mx, __shfl_xor(mx, off));
            float mo = mrun[row];
            float mn = fmaxf(mo, mx);
            float p0 = __expf(SCALE * (x0 - mn)), p1 = __expf(SCALE * (x1 - mn));
            float ps = p0 + p1;
#pragma unroll
            for (int off = 16; off >= 1; off >>= 1) ps += __shfl_xor(ps, off);
            if (cl == 0) {
                float rt_ = __expf(SCALE * (mo - mn));
                ratio_s[row] = rt_;
                lrun[row] = lrun[row] * rt_ + ps;
                mrun[row] = mn;
            }
            *(uint32*)&PbB[row * 128 + ((cl * 4) ^ ((row & 7) << 4))] = pk2(p0, p1);
        }
        __syncthreads();   // (C) Pb, ratio ready

        // ---- PV: rescale + P@V over this wave's 96 cols ----
        {
            float rr[4];
#pragma unroll
            for (int r = 0; r < 4; ++r) rr[r] = ratio_s[g * 4 + r];
#pragma unroll
            for (int ct = 0; ct < 6; ++ct)
#pragma unroll
                for (int r = 0; r < 4; ++r) o[ct][r] *= rr[r];

            bf16x8 pa[2];
#pragma unroll
            for (int ks = 0; ks < 2; ++ks)
                pa[ks] = *(const bf16x8*)&PbB[li * 128 + ((ks * 64 + g * 16) ^ ((li & 7) << 4))];

            const ushort* vj = vrow + jt * 64;
            union U16 { uint4 u; bf16x8 bv; };
#pragma unroll
            for (int ct = 0; ct < 6; ++ct) {
                U16 va, vb;
                va.u = *(const uint4*)(vj + (size_t)ct * 32768);
                vb.u = *(const uint4*)(vj + (size_t)ct * 32768 + 32);
                o[ct] = __builtin_amdgcn_mfma_f32_16x16x32_bf16(pa[0], va.bv, o[ct], 0, 0, 0);
                o[ct] = __builtin_amdgcn_mfma_f32_16x16x32_bf16(pa[1], vb.bv, o[ct], 0, 0, 0);
            }
        }
        // next K-stage touches only KbB; its readers finished before (B). Safe with (A).
    }

    // ---- finalize: /l, gate u in place ----
    {
        float inv[4];
#pragma unroll
        for (int r = 0; r < 4; ++r) inv[r] = 1.0f / lrun[g * 4 + r];
#pragma unroll
        for (int r = 0; r < 4; ++r) {
            float* ub = u_buf + (rowQ0 + g * 4 + r) * 768;
#pragma unroll
            for (int ct = 0; ct < 6; ++ct) {
                int col = w * 96 + ct * 16 + li;
                ub[col] = o[ct][r] * inv[r] * ub[col];
            }
        }
    }
}

extern "C" void kernel_launch(void* const* d_in, const int* in_sizes, int n_in,
                              void* d_out, int out_size, void* d_ws, size_t ws_size,
                              hipStream_t stream)
{
    const float* x    = (const float*)d_in[0];   // [8,2048,384]
    const float* pos  = (const float*)d_in[1];   // [1,2048,256]
    const float* Wuv  = (const float*)d_in[2];   // [384,1792]
    const float* Wout = (const float*)d_in[3];   // [768,384]
    float* out = (float*)d_out;                  // [8,2048,384] f32

    float*  u_buf = (float*)d_ws;                        // 16384*768 f32
    ushort* qk    = (ushort*)(u_buf + (size_t)R_ * HID); // 16384*256 bf16
    ushort* vT    = qk + (size_t)R_ * 256;               // 8*768*2048 bf16
    ushort* WuvThi  = vT + (size_t)B_ * HID * L_;
    ushort* WuvTlo  = WuvThi + (size_t)NUV * D2;
    ushort* WoutThi = WuvTlo + (size_t)NUV * D2;
    ushort* WoutTlo = WoutThi + (size_t)D2 * HID;

    size_t need = ((size_t)R_ * HID) * 4 +
                  ((size_t)R_ * 256 + (size_t)B_ * HID * L_ +
                   2 * (size_t)NUV * D2 + 2 * (size_t)D2 * HID) * 2;
    if (ws_size < need) return;

    conv_w<<<dim3((D2 * NUV + 255) / 256), dim3(256), 0, stream>>>(Wuv, WuvThi, WuvTlo, D2, NUV);
    conv_w<<<dim3((HID * D2 + 255) / 256), dim3(256), 0, stream>>>(Wout, WoutThi, WoutTlo, HID, D2);

    gemm_mfma<1><<<dim3(NUV / 128, R_ / 128), dim3(512), 0, stream>>>(
        x, D2, WuvThi, WuvTlo, D2, u_buf, HID, qk, vT, D2);

    rope_bf<<<dim3(R_), dim3(128), 0, stream>>>(qk, pos);

    fused_attn3<<<dim3(1024), dim3(512), 0, stream>>>(u_buf, qk, vT);

    gemm_mfma<0><<<dim3(D2 / 128, R_ / 128), dim3(512), 0, stream>>>(
        u_buf, HID, WoutThi, WoutTlo, HID, out, D2, nullptr, nullptr, HID);
}

// Round 7
// 551.778 us; speedup vs baseline: 1.1188x; 1.1188x over previous
//
#include <hip/hip_runtime.h>
#include <hip/hip_bf16.h>
#include <math.h>

#define B_    8
#define L_    2048
#define HID   768
#define D2    384
#define NUV   1792
#define R_    16384
#define SCALE 0.08838834764831845f  // 128^-0.5

typedef __attribute__((ext_vector_type(8))) short bf16x8;
typedef __attribute__((ext_vector_type(4))) float f32x4;
typedef unsigned int uint32;
typedef unsigned short ushort;

static __device__ __forceinline__ uint32 bfr(float x) {
    uint32 u = __float_as_uint(x);
    return (u + 0x7FFFu + ((u >> 16) & 1u)) >> 16;
}
static __device__ __forceinline__ uint32 pk2(float lo, float hi) {
    return bfr(lo) | (bfr(hi) << 16);
}
static __device__ __forceinline__ float bf2f(ushort u) {
    return __uint_as_float(((uint32)u) << 16);
}
static __device__ __forceinline__ float silu_f(float x) { return x / (1.0f + __expf(-x)); }

// ---------------------------------------------------------------------------
// Weight pre-transform: Thi/Tlo[n][k] = bf16 hi/lo split of W[k][n]
// ---------------------------------------------------------------------------
__global__ __launch_bounds__(256) void conv_w(const float* __restrict__ W,
                                              ushort* __restrict__ Thi,
                                              ushort* __restrict__ Tlo,
                                              int K, int N)
{
    int idx = blockIdx.x * 256 + threadIdx.x;
    if (idx >= K * N) return;
    int n = idx / K, k = idx - n * K;
    float x = W[(size_t)k * N + n];
    uint32 h = bfr(x);
    float hf = __uint_as_float(h << 16);
    Thi[idx] = (ushort)h;
    Tlo[idx] = (ushort)bfr(x - hf);
}

// ---------------------------------------------------------------------------
// Split-bf16 MFMA GEMM (3-pass hi/lo). B pre-transposed+split [N][K] bf16.
// Block 512 thr (8 waves), tile 128x128, BK=64.
// EPI 0: C f32     EPI 1: GAU GEMM1 epilogue (u/v/qk by n0)
// ---------------------------------------------------------------------------
template<int EPI>
__global__ __launch_bounds__(512, 4) void gemm_mfma(
    const float* __restrict__ A, int lda,
    const ushort* __restrict__ BThi, const ushort* __restrict__ BTlo, int ldbt,
    float* __restrict__ C, int ldc,
    ushort* __restrict__ qk, ushort* __restrict__ vT, int K)
{
    __shared__ unsigned char As[128 * 256];
    __shared__ unsigned char Bs[128 * 256];

    const int t  = threadIdx.x;
    const int w  = t >> 6;
    const int l  = t & 63;
    const int g  = l >> 4;
    const int li = l & 15;
    const int wr = w >> 1;
    const int wc = w & 1;
    const int m0 = blockIdx.y * 128;
    const int n0 = blockIdx.x * 128;

    f32x4 acc[2][4];
#pragma unroll
    for (int i = 0; i < 2; ++i)
#pragma unroll
        for (int j = 0; j < 4; ++j) acc[i][j] = (f32x4){0.f, 0.f, 0.f, 0.f};

    for (int k0 = 0; k0 < K; k0 += 64) {
#pragma unroll
        for (int i = 0; i < 4; ++i) {
            int idx = t + i * 512;
            int r   = idx >> 4;
            int c16 = idx & 15;
            float4 v = *(const float4*)(A + (long long)(m0 + r) * lda + k0 + c16 * 4);
            uint2 h; h.x = pk2(v.x, v.y); h.y = pk2(v.z, v.w);
            float hx = __uint_as_float((h.x & 0xFFFFu) << 16), hy = __uint_as_float(h.x & 0xFFFF0000u);
            float hz = __uint_as_float((h.y & 0xFFFFu) << 16), hw = __uint_as_float(h.y & 0xFFFF0000u);
            uint2 lo; lo.x = pk2(v.x - hx, v.y - hy); lo.y = pk2(v.z - hz, v.w - hw);
            int sw = (c16 * 8) ^ ((r & 7) << 4);
            *(uint2*)&As[r * 256 + sw]       = h;
            *(uint2*)&As[r * 256 + 128 + sw] = lo;
        }
#pragma unroll
        for (int i = 0; i < 8; ++i) {
            int idx = t + i * 512;
            int c   = idx >> 5;
            int s8  = idx & 31;
            const ushort* src = (s8 < 16)
                ? (BThi + (long long)(n0 + c) * ldbt + k0 + s8 * 4)
                : (BTlo + (long long)(n0 + c) * ldbt + k0 + (s8 - 16) * 4);
            *(uint2*)&Bs[c * 256 + ((s8 * 8) ^ ((c & 7) << 4))] = *(const uint2*)src;
        }
        __syncthreads();

#pragma unroll
        for (int ks = 0; ks < 2; ++ks) {
            bf16x8 ah[2], al[2], bh[4], bl[4];
#pragma unroll
            for (int mi = 0; mi < 2; ++mi) {
                int row = wr * 32 + mi * 16 + li;
                int off = (ks * 64 + g * 16) ^ ((row & 7) << 4);
                ah[mi] = *(const bf16x8*)&As[row * 256 + off];
                al[mi] = *(const bf16x8*)&As[row * 256 + 128 + off];
            }
#pragma unroll
            for (int ni = 0; ni < 4; ++ni) {
                int col = wc * 64 + ni * 16 + li;
                int off = (ks * 64 + g * 16) ^ ((col & 7) << 4);
                bh[ni] = *(const bf16x8*)&Bs[col * 256 + off];
                bl[ni] = *(const bf16x8*)&Bs[col * 256 + 128 + off];
            }
#pragma unroll
            for (int mi = 0; mi < 2; ++mi)
#pragma unroll
                for (int ni = 0; ni < 4; ++ni) {
                    acc[mi][ni] = __builtin_amdgcn_mfma_f32_16x16x32_bf16(ah[mi], bh[ni], acc[mi][ni], 0, 0, 0);
                    acc[mi][ni] = __builtin_amdgcn_mfma_f32_16x16x32_bf16(ah[mi], bl[ni], acc[mi][ni], 0, 0, 0);
                    acc[mi][ni] = __builtin_amdgcn_mfma_f32_16x16x32_bf16(al[mi], bh[ni], acc[mi][ni], 0, 0, 0);
                }
        }
        __syncthreads();
    }

    if (EPI == 0) {
#pragma unroll
        for (int mi = 0; mi < 2; ++mi)
#pragma unroll
            for (int ni = 0; ni < 4; ++ni) {
                int col = n0 + wc * 64 + ni * 16 + li;
#pragma unroll
                for (int r = 0; r < 4; ++r) {
                    int row = m0 + wr * 32 + mi * 16 + g * 4 + r;
                    C[(long long)row * ldc + col] = acc[mi][ni][r];
                }
            }
    } else {
        if (n0 < 768) {
#pragma unroll
            for (int mi = 0; mi < 2; ++mi)
#pragma unroll
                for (int ni = 0; ni < 4; ++ni) {
                    int col = n0 + wc * 64 + ni * 16 + li;
#pragma unroll
                    for (int r = 0; r < 4; ++r) {
                        int row = m0 + wr * 32 + mi * 16 + g * 4 + r;
                        C[(long long)row * 768 + col] = silu_f(acc[mi][ni][r]);
                    }
                }
        } else if (n0 < 1536) {
            int bb = m0 >> 11;
            int llb = (m0 & 2047) + wr * 32 + g * 4;
#pragma unroll
            for (int mi = 0; mi < 2; ++mi) {
                int ll = llb + mi * 16;
#pragma unroll
                for (int ni = 0; ni < 4; ++ni) {
                    int cv = n0 + wc * 64 + ni * 16 + li - 768;
                    ushort* vb = vT + ((size_t)bb * 768 + cv) * 2048 + ll;
                    *(uint32*)(vb)     = pk2(silu_f(acc[mi][ni][0]), silu_f(acc[mi][ni][1]));
                    *(uint32*)(vb + 2) = pk2(silu_f(acc[mi][ni][2]), silu_f(acc[mi][ni][3]));
                }
            }
        } else {
#pragma unroll
            for (int mi = 0; mi < 2; ++mi)
#pragma unroll
                for (int ni = 0; ni < 4; ++ni) {
                    int qcol = n0 + wc * 64 + ni * 16 + li - 1536;
#pragma unroll
                    for (int r = 0; r < 4; ++r) {
                        int row = m0 + wr * 32 + mi * 16 + g * 4 + r;
                        qk[(size_t)row * 256 + qcol] = (ushort)bfr(acc[mi][ni][r]);
                    }
                }
        }
    }
}

// ---------------------------------------------------------------------------
// RoPE in place on bf16 qk buffer (q cols 0..127, k cols 128..255)
// ---------------------------------------------------------------------------
__global__ __launch_bounds__(128) void rope_bf(ushort* __restrict__ qk,
                                               const float* __restrict__ pos)
{
    int row = blockIdx.x;
    int lpos = row & (L_ - 1);
    int t = threadIdx.x;
    int j = t & 63;
    int isK = t >> 6;
    ushort* base = qk + (size_t)row * 256 + isK * 128;
    float s = pos[lpos * 256 + j];
    float c = pos[lpos * 256 + 64 + j];
    float x1 = bf2f(base[j]);
    float x2 = bf2f(base[64 + j]);
    base[j]      = (ushort)bfr(x1 * c - x2 * s);
    base[64 + j] = (ushort)bfr(x2 * c + x1 * s);
}

// ---------------------------------------------------------------------------
// MFMA flash attention v4 — independent waves, barrier-lite.
// QBLK=16 q-rows/block, 512 thr (8 waves), grid 1024 (4 blocks/CU).
// Each wave: FULL 16x64 QK tile (redundant across waves) + in-register
// online softmax (m/l/ratio per lane, no LDS stats) + PV for its 96 V-cols.
// Cross-wave coupling ONLY via K-tile LDS staging: 2 barriers/tile.
// P transpose via private 2KB per-wave LDS (XOR-swizzled).
// ---------------------------------------------------------------------------
__global__ __launch_bounds__(512) void fused_attn4(
    float* __restrict__ u_buf, const ushort* __restrict__ qk,
    const ushort* __restrict__ vT)
{
    __shared__ unsigned char KbB[64 * 256];        // K tile bf16 [64][128], swizzled
    __shared__ unsigned char PbB[8][16 * 128];     // per-wave P bf16 [16][64], swizzled

    const int t  = threadIdx.x;
    const int w  = t >> 6;
    const int l  = t & 63;
    const int g  = l >> 4;
    const int li = l & 15;

    const int b  = blockIdx.x & 7;                 // XCD-pinned batch
    const int qt = blockIdx.x >> 3;                // 0..127
    const long long rowQ0 = (long long)b * L_ + (long long)qt * 16;
    const long long rowB0 = (long long)b * L_;

    // ---- Q A-frags: row li, k = ks*32 + g*8 ----
    bf16x8 qf[4];
    {
        const ushort* qrow = qk + (rowQ0 + li) * 256;
#pragma unroll
        for (int ks = 0; ks < 4; ++ks)
            qf[ks] = *(const bf16x8*)&qrow[ks * 32 + g * 8];
    }

    float m_run[4], l_run[4];
#pragma unroll
    for (int r = 0; r < 4; ++r) { m_run[r] = -3.0e38f; l_run[r] = 0.0f; }

    f32x4 o[6];
#pragma unroll
    for (int ct = 0; ct < 6; ++ct) o[ct] = (f32x4){0.f, 0.f, 0.f, 0.f};

    unsigned char* Pw = &PbB[w][0];
    const ushort* vrow = vT + ((size_t)b * 768 + w * 96 + li) * 2048 + g * 8;

    // K staging address precompute (thread-fixed)
    const int kr0 = t >> 4;            // rows for it=0: 0..31
    const int ks16 = t & 15;
    const int kr1 = kr0 + 32;          // rows for it=1: 32..63

    // prefetch K tile 0 into regs
    uint4 kreg0 = *(const uint4*)&qk[(rowB0 + kr0) * 256 + 128 + ks16 * 8];
    uint4 kreg1 = *(const uint4*)&qk[(rowB0 + kr1) * 256 + 128 + ks16 * 8];

    for (int jt = 0; jt < L_ / 64; ++jt) {
        // ---- publish staged K tile ----
        *(uint4*)&KbB[kr0 * 256 + ((ks16 * 16) ^ ((kr0 & 7) << 4))] = kreg0;
        *(uint4*)&KbB[kr1 * 256 + ((ks16 * 16) ^ ((kr1 & 7) << 4))] = kreg1;
        __syncthreads();   // (A) K ready

        // prefetch next K tile (latency hidden under compute below)
        if (jt + 1 < L_ / 64) {
            kreg0 = *(const uint4*)&qk[(rowB0 + (jt + 1) * 64 + kr0) * 256 + 128 + ks16 * 8];
            kreg1 = *(const uint4*)&qk[(rowB0 + (jt + 1) * 64 + kr1) * 256 + 128 + ks16 * 8];
        }

        // ---- QK: full 16x64 S tile per wave (redundant, independent) ----
        f32x4 s[4];
#pragma unroll
        for (int ct = 0; ct < 4; ++ct) {
            s[ct] = (f32x4){0.f, 0.f, 0.f, 0.f};
            const int krow = ct * 16 + li;
#pragma unroll
            for (int ks = 0; ks < 4; ++ks) {
                bf16x8 kf = *(const bf16x8*)&KbB[krow * 256 +
                                ((ks * 64 + g * 16) ^ ((krow & 7) << 4))];
                s[ct] = __builtin_amdgcn_mfma_f32_16x16x32_bf16(qf[ks], kf, s[ct], 0, 0, 0);
            }
        }

        // ---- in-register online softmax (rows g*4+r, 16 li-lanes each) ----
        float ratio[4];
#pragma unroll
        for (int r = 0; r < 4; ++r) {
            float mx = fmaxf(fmaxf(s[0][r], s[1][r]), fmaxf(s[2][r], s[3][r]));
#pragma unroll
            for (int off = 8; off >= 1; off >>= 1) mx = fmaxf(mx, __shfl_xor(mx, off));
            float mn = fmaxf(m_run[r], mx);
            ratio[r] = __expf(SCALE * (m_run[r] - mn));
            m_run[r] = mn;

            float p0 = __expf(SCALE * (s[0][r] - mn));
            float p1 = __expf(SCALE * (s[1][r] - mn));
            float p2 = __expf(SCALE * (s[2][r] - mn));
            float p3 = __expf(SCALE * (s[3][r] - mn));
            float ps = p0 + p1 + p2 + p3;
#pragma unroll
            for (int off = 8; off >= 1; off >>= 1) ps += __shfl_xor(ps, off);
            l_run[r] = l_run[r] * ratio[r] + ps;

            // write P row (g*4+r) to private swizzled LDS
            const int row = g * 4 + r;
            const int rs = (row & 7) << 4;
            *(ushort*)&Pw[row * 128 + (((0 * 16 + li) * 2) ^ rs)] = (ushort)bfr(p0);
            *(ushort*)&Pw[row * 128 + (((1 * 16 + li) * 2) ^ rs)] = (ushort)bfr(p1);
            *(ushort*)&Pw[row * 128 + (((2 * 16 + li) * 2) ^ rs)] = (ushort)bfr(p2);
            *(ushort*)&Pw[row * 128 + (((3 * 16 + li) * 2) ^ rs)] = (ushort)bfr(p3);
        }

        // ---- rescale accumulators ----
#pragma unroll
        for (int ct = 0; ct < 6; ++ct)
#pragma unroll
            for (int r = 0; r < 4; ++r) o[ct][r] *= ratio[r];

        // ---- read P A-frags (same wave; compiler inserts lgkmcnt) ----
        bf16x8 pa0 = *(const bf16x8*)&Pw[li * 128 + ((0 * 64 + g * 16) ^ ((li & 7) << 4))];
        bf16x8 pa1 = *(const bf16x8*)&Pw[li * 128 + ((1 * 64 + g * 16) ^ ((li & 7) << 4))];

        // ---- PV: 96 private V-cols, V direct from L2, 2-deep pipeline ----
        {
            const ushort* vj = vrow + jt * 64;
            union U16 { uint4 u; bf16x8 bv; };
            U16 va, vb;
            va.u = *(const uint4*)(vj);
            vb.u = *(const uint4*)(vj + 32);
#pragma unroll
            for (int ct = 0; ct < 6; ++ct) {
                U16 na, nb;
                if (ct < 5) {
                    na.u = *(const uint4*)(vj + (size_t)(ct + 1) * 32768);
                    nb.u = *(const uint4*)(vj + (size_t)(ct + 1) * 32768 + 32);
                } else { na = va; nb = vb; }
                o[ct] = __builtin_amdgcn_mfma_f32_16x16x32_bf16(pa0, va.bv, o[ct], 0, 0, 0);
                o[ct] = __builtin_amdgcn_mfma_f32_16x16x32_bf16(pa1, vb.bv, o[ct], 0, 0, 0);
                va = na; vb = nb;
            }
        }
        __syncthreads();   // (B) all waves done with KbB before next publish
    }

    // ---- finalize: /l, gate u in place ----
    {
        float inv[4];
#pragma unroll
        for (int r = 0; r < 4; ++r) inv[r] = 1.0f / l_run[r];
#pragma unroll
        for (int r = 0; r < 4; ++r) {
            float* ub = u_buf + (rowQ0 + g * 4 + r) * 768;
#pragma unroll
            for (int ct = 0; ct < 6; ++ct) {
                int col = w * 96 + ct * 16 + li;
                ub[col] = o[ct][r] * inv[r] * ub[col];
            }
        }
    }
}

extern "C" void kernel_launch(void* const* d_in, const int* in_sizes, int n_in,
                              void* d_out, int out_size, void* d_ws, size_t ws_size,
                              hipStream_t stream)
{
    const float* x    = (const float*)d_in[0];   // [8,2048,384]
    const float* pos  = (const float*)d_in[1];   // [1,2048,256]
    const float* Wuv  = (const float*)d_in[2];   // [384,1792]
    const float* Wout = (const float*)d_in[3];   // [768,384]
    float* out = (float*)d_out;                  // [8,2048,384] f32

    float*  u_buf = (float*)d_ws;                        // 16384*768 f32
    ushort* qk    = (ushort*)(u_buf + (size_t)R_ * HID); // 16384*256 bf16
    ushort* vT    = qk + (size_t)R_ * 256;               // 8*768*2048 bf16
    ushort* WuvThi  = vT + (size_t)B_ * HID * L_;
    ushort* WuvTlo  = WuvThi + (size_t)NUV * D2;
    ushort* WoutThi = WuvTlo + (size_t)NUV * D2;
    ushort* WoutTlo = WoutThi + (size_t)D2 * HID;

    size_t need = ((size_t)R_ * HID) * 4 +
                  ((size_t)R_ * 256 + (size_t)B_ * HID * L_ +
                   2 * (size_t)NUV * D2 + 2 * (size_t)D2 * HID) * 2;
    if (ws_size < need) return;

    conv_w<<<dim3((D2 * NUV + 255) / 256), dim3(256), 0, stream>>>(Wuv, WuvThi, WuvTlo, D2, NUV);
    conv_w<<<dim3((HID * D2 + 255) / 256), dim3(256), 0, stream>>>(Wout, WoutThi, WoutTlo, HID, D2);

    gemm_mfma<1><<<dim3(NUV / 128, R_ / 128), dim3(512), 0, stream>>>(
        x, D2, WuvThi, WuvTlo, D2, u_buf, HID, qk, vT, D2);

    rope_bf<<<dim3(R_), dim3(128), 0, stream>>>(qk, pos);

    fused_attn4<<<dim3(1024), dim3(512), 0, stream>>>(u_buf, qk, vT);

    gemm_mfma<0><<<dim3(D2 / 128, R_ / 128), dim3(512), 0, stream>>>(
        u_buf, HID, WoutThi, WoutTlo, HID, out, D2, nullptr, nullptr, HID);
}